// Round 13
// baseline (712.736 us; speedup 1.0000x reference)
//
#include <hip/hip_runtime.h>

#define NV 8192
#define NC 128
#define VP 64
#define FP 124
#define MAXSLOT 26   // bbox half-extent <= 0.5, spacing 0.8 -> <=26 neighbors
#define NSL 7        // max slots per wave = ceil(26/4)

typedef unsigned long long ull;

// ---- lock-free union-find on global parent[] ----
// Invariant: parent[x] <= x, monotone decreasing -> stale reads are valid
// older parents; walks strictly descend -> terminate. atomicMin returns
// drive the retry loop (authoritative).
__device__ __forceinline__ int findro(const int* parent, int x) {
  int p = parent[x];
  while (p != x) { x = p; p = parent[x]; }
  return x;
}
__device__ __forceinline__ void ghook(int* parent, int a0, int b0) {
  int a = a0, b = b0;
  for (;;) {
    a = findro(parent, a);
    b = findro(parent, b);
    if (a == b) break;
    int hi = a > b ? a : b, lo = a > b ? b : a;
    int old = atomicMin(&parent[hi], lo);
    if (old == hi) { a = lo; b = lo; break; }
    a = old; b = lo;
  }
  int r = a < b ? a : b;
  if (r < a0) atomicMin(&parent[a0], r);   // one-shot path compression
  if (r < b0) atomicMin(&parent[b0], r);
}

// Vertex reconstruction from group-mean sums (identical expression at every
// call site -> bitwise-identical coordinates in all blocks).
__device__ __forceinline__ void recon3(const float* ps1, const float* ps2,
                                       const float* pc, int l,
                                       float& x, float& y, float& z) {
  float cc = fmaxf(pc[l], 1.f);
  x = ps1[3*l+0]/cc + 1e-5f*(ps2[3*l+0]/cc);
  y = ps1[3*l+1]/cc + 1e-5f*(ps2[3*l+1]/cc);
  z = ps1[3*l+2]/cc + 1e-5f*(ps2[3*l+2]/cc);
}

// Shared adjacency derivation: parity-balanced pair ownership.
__device__ __forceinline__ int build_adj(const float* bb, int c, int q, int v,
                                         int t, int* s_hcell, ull* s_adjw,
                                         int* s_KH) {
  if (q < 2) {
    int b = q * 64 + v;
    float anx = bb[c*6+0], any_ = bb[c*6+1], anz = bb[c*6+2];
    float axx = bb[c*6+3], axy = bb[c*6+4], axz = bb[c*6+5];
    float bnx = bb[b*6+0], bny = bb[b*6+1], bnz = bb[b*6+2];
    float bxx = bb[b*6+3], bxy = bb[b*6+4], bxz = bb[b*6+5];
    bool ov = (b != c) && (anx <= bxx) && (any_ <= bxy) && (anz <= bxz) &&
              (bnx <= axx) && (bny <= axy) && (bnz <= axz);
    bool mine = ov && (((c + b) & 1) ? (b < c) : (b > c));
    ull w = __ballot(mine);
    if (v == 0) s_adjw[q] = w;
  }
  __syncthreads();
  if (t == 0) {
    int slot = 0;
    for (int wd = 0; wd < 2; ++wd) {
      ull aw = s_adjw[wd];
      while (aw) {
        int bbit = __ffsll((long long)aw) - 1; aw &= aw - 1;
        if (slot < MAXSLOT) s_hcell[slot] = wd * 64 + bbit;
        ++slot;
      }
    }
    *s_KH = slot;
  }
  __syncthreads();
  return *s_KH;
}

__global__ void k_init(int* __restrict__ parent) {
  int i = blockIdx.x * blockDim.x + threadIdx.x;
  if (i < NV) parent[i] = i;
}

// K1: stage verts (input or recon), contact masks, clique labels.
// NO global UF work -- publishes llab + masks for k_hook.
__global__ __launch_bounds__(256, 1)
void k_contact(int it, const float* __restrict__ inV, const float* __restrict__ bb,
               const int* __restrict__ labelsF, const float* __restrict__ ps1,
               const float* __restrict__ pc, const float* __restrict__ ps2,
               float* __restrict__ verts, int* __restrict__ llab,
               ull* __restrict__ masks) {
  const float T2 = (float)(0.3 * 0.3);
  const int c = blockIdx.x;
  const int t = threadIdx.x;
  const int q = t >> 6;
  const int v = t & 63;

  __shared__ float s_vx[VP], s_vy[VP], s_vz[VP], s_sq[VP];
  __shared__ int   s_ll[VP];
  __shared__ int   s_hcell[MAXSLOT];
  __shared__ int   s_KH, s_cf;
  __shared__ ull   s_adjw[2];

  const int KH = build_adj(bb, c, q, v, t, s_hcell, s_adjw, &s_KH);
  if (t == 0) s_cf = 0;

  if (t < VP) {
    int i = c*VP + t;
    float x, y, z;
    if (it == 0) { x = inV[3*i+0]; y = inV[3*i+1]; z = inV[3*i+2]; }
    else         { recon3(ps1, ps2, pc, labelsF[i], x, y, z); }
    s_vx[t] = x; s_vy[t] = y; s_vz[t] = z; s_sq[t] = x*x + y*y + z*z;
    s_ll[t] = t;
    verts[3*i+0] = x; verts[3*i+1] = y; verts[3*i+2] = z;  // for K3's scatter
  }
  __syncthreads();

  ull msk[NSL];
  {
    float xs[NSL], ys[NSL], zs[NSL];
#pragma unroll
    for (int s = 0; s < NSL; ++s) {
      msk[s] = 0;
      int slot = q + 4*s;
      if (slot < KH) {
        int jb = s_hcell[slot]*VP;
        if (it == 0) {
          int j = jb + v;
          xs[s] = inV[3*j+0]; ys[s] = inV[3*j+1]; zs[s] = inV[3*j+2];
        } else {
          int lF = labelsF[jb + v];
          recon3(ps1, ps2, pc, lF, xs[s], ys[s], zs[s]);
        }
      }
    }
#pragma unroll
    for (int s = 0; s < NSL; ++s) { int slot = q + 4*s; if (slot < KH) {
      float X = xs[s], Y = ys[s], Z = zs[s];
      float sqj = X*X + Y*Y + Z*Z;
      ull w = 0;
      for (int vv = 0; vv < VP; ++vv) {
        float d2 = s_sq[vv] + sqj - 2.f*(s_vx[vv]*X + s_vy[vv]*Y + s_vz[vv]*Z);
        if (d2 < T2) w |= (1ull << vv);
      }
      msk[s] = w;
      masks[((size_t)c*MAXSLOT + slot)*VP + v] = w;
    } }
  }

  // clique min-label propagation to fixpoint (each mask = one clique).
  // At fixpoint every clique is label-uniform (k_hook relies on this).
  {
    int rounds = 0;
    for (;;) {
      bool chg = false;
#pragma unroll
      for (int s = 0; s < NSL; ++s) { if (msk[s]) {
        ull m = msk[s]; int mn = VP;
        while (m) { int b = __ffsll((long long)m) - 1; m &= m - 1;
                    mn = min(mn, s_ll[b]); }
        m = msk[s];
        while (m) { int b = __ffsll((long long)m) - 1; m &= m - 1;
                    if (s_ll[b] > mn) { atomicMin(&s_ll[b], mn); chg = true; } }
      } }
      if (chg) s_cf = 1;
      __syncthreads();
      int done = (s_cf == 0);
      __syncthreads();
      if (t == 0) s_cf = 0;
      ++rounds;
      if (done || rounds >= VP) break;
      __syncthreads();
    }
  }
  if (t < VP) llab[c*VP + t] = c*VP + s_ll[t];
}

// K2: quotient-space hooks. Both sides' local labels now visible ->
// wave-dedupe identical (L, Lb) pairs; ~a few ghooks per slot.
__global__ __launch_bounds__(256, 1)
void k_hook(const float* __restrict__ bb, const int* __restrict__ llab,
            const ull* __restrict__ masks, int* __restrict__ parent) {
  const int c = blockIdx.x;
  const int t = threadIdx.x;
  const int q = t >> 6;
  const int v = t & 63;

  __shared__ int s_hcell[MAXSLOT];
  __shared__ int s_KH;
  __shared__ ull s_adjw[2];

  const int KH = build_adj(bb, c, q, v, t, s_hcell, s_adjw, &s_KH);

#pragma unroll
  for (int s = 0; s < NSL; ++s) { int slot = q + 4*s; if (slot < KH) {
    int jb = s_hcell[slot]*VP;
    ull w = masks[((size_t)c*MAXSLOT + slot)*VP + v];
    int L = -1, Lb = -1;
    if (w) {
      L  = llab[c*VP + (__ffsll((long long)w) - 1)];  // clique-uniform
      Lb = llab[jb + v];
    }
    ull act = __ballot(w != 0);
    while (act) {
      int lead = __ffsll((long long)act) - 1;
      int Ll  = __shfl(L,  lead);
      int Lbl = __shfl(Lb, lead);
      ull grp = __ballot(L == Ll && Lb == Lbl && w != 0) & act;
      if (v == lead) ghook(parent, Ll, Lbl);
      act &= ~grp;
    }
  } }
}

// K3: find labels (starting at llab), publish, zero prev parity, scatter.
__global__ __launch_bounds__(64, 1)
void k_find(const int* __restrict__ parent, const int* __restrict__ llab,
            int* __restrict__ labelsF, const float* __restrict__ verts,
            float* __restrict__ cs1, float* __restrict__ cc1,
            float* __restrict__ zs1, float* __restrict__ zc,
            float* __restrict__ zs2) {
  const int c = blockIdx.x, t = threadIdx.x;
  __shared__ int   s_lab[VP];
  __shared__ float s_vx[VP], s_vy[VP], s_vz[VP];
  int i = c*VP + t;
  int l = findro(parent, llab[i]);
  s_lab[t] = l;
  labelsF[i] = l;
  s_vx[t] = verts[3*i+0]; s_vy[t] = verts[3*i+1]; s_vz[t] = verts[3*i+2];
  for (int idx = t; idx < VP*3; idx += VP) {
    zs1[c*VP*3 + idx] = 0.f;   // prev parity: dead after K1, ready for it+1
    zs2[c*VP*3 + idx] = 0.f;
  }
  zc[i] = 0.f;
  __syncthreads();
  {
    bool leader = true;
    for (int s = 0; s < t; ++s) if (s_lab[s] == l) { leader = false; break; }
    if (leader) {
      float sx = 0.f, sy = 0.f, sz = 0.f, cn = 0.f;
      for (int s = t; s < VP; ++s)
        if (s_lab[s] == l) { sx += s_vx[s]; sy += s_vy[s]; sz += s_vz[s]; cn += 1.f; }
      atomicAdd(&cs1[3*l+0], sx);
      atomicAdd(&cs1[3*l+1], sy);
      atomicAdd(&cs1[3*l+2], sz);
      atomicAdd(&cc1[l], cn);
    }
  }
}

// K4: gather group-mean verts, cell forces, scatter force sums, parent reinit.
__global__ __launch_bounds__(128, 1)
void k_forces(const int* __restrict__ labelsF, const int* __restrict__ faces,
              const int* __restrict__ cfl, const float* __restrict__ pP,
              const float* __restrict__ pS,
              const float* __restrict__ cs1, const float* __restrict__ cc1,
              float* __restrict__ cs2, int* __restrict__ parent) {
  const int c = blockIdx.x, t = threadIdx.x;
  __shared__ float s_vx[VP], s_vy[VP], s_vz[VP];
  __shared__ float s_gx[VP], s_gy[VP], s_gz[VP];
  __shared__ float s_fx[VP], s_fy[VP], s_fz[VP];
  __shared__ int   s_lab[VP];
  __shared__ float s_cx, s_cy, s_cz, s_vol, s_csx, s_csy, s_csz;

  if (t < VP) {
    int i = c*VP + t;
    int l = labelsF[i];
    s_lab[t] = l;
    float cc = fmaxf(cc1[l], 1.f);
    s_vx[t] = cs1[3*l+0] / cc;
    s_vy[t] = cs1[3*l+1] / cc;
    s_vz[t] = cs1[3*l+2] / cc;
    s_gx[t] = 0.f; s_gy[t] = 0.f; s_gz[t] = 0.f;
    parent[i] = i;   // reinit for next iteration
  }
  if (t == 0) { s_vol = 0.f; s_csx = 0.f; s_csy = 0.f; s_csz = 0.f; }
  __syncthreads();
  if (t < VP) {
    float sx = s_vx[t], sy = s_vy[t], sz = s_vz[t];
#pragma unroll
    for (int o = 32; o; o >>= 1) { sx += __shfl_xor(sx, o); sy += __shfl_xor(sy, o); sz += __shfl_xor(sz, o); }
    if (t == 0) { s_cx = sx*(1.f/VP); s_cy = sy*(1.f/VP); s_cz = sz*(1.f/VP); }
  }
  __syncthreads();
  float cx = s_cx, cy = s_cy, cz = s_cz;
  bool act = (t < FP);
  int ia = 0, ib = 0, ic = 0;
  float p0x=0,p0y=0,p0z=0,p1x=0,p1y=0,p1z=0,p2x=0,p2y=0,p2z=0;
  float q0x=0,q0y=0,q0z=0;
  if (act) {
    int f = cfl[c*FP + t];
    ia = faces[3*f+0] - c*VP; ib = faces[3*f+1] - c*VP; ic = faces[3*f+2] - c*VP;
    p0x = s_vx[ia]-cx; p0y = s_vy[ia]-cy; p0z = s_vz[ia]-cz;
    p1x = s_vx[ib]-cx; p1y = s_vy[ib]-cy; p1z = s_vz[ib]-cz;
    p2x = s_vx[ic]-cx; p2y = s_vy[ic]-cy; p2z = s_vz[ic]-cz;
    q0x = p1y*p2z - p1z*p2y;
    q0y = p1z*p2x - p1x*p2z;
    q0z = p1x*p2y - p1y*p2x;
    float term = p0x*q0x + p0y*q0y + p0z*q0z;
    atomicAdd(&s_vol, term);
  }
  __syncthreads();
  float press = pP[0]*190.f + 10.f;
  float st    = pS[0]*0.018f + 0.002f;
  float tv    = expf(press / 2500.f);
  float vol   = s_vol / 6.f;
  float coeff = 2500.f * (vol - tv);
  if (act) {
    float q1x = p2y*p0z - p2z*p0y;
    float q1y = p2z*p0x - p2x*p0z;
    float q1z = p2x*p0y - p2y*p0x;
    float q2x = p0y*p1z - p0z*p1y;
    float q2y = p0z*p1x - p0x*p1z;
    float q2z = p0x*p1y - p0y*p1x;
    float e1x = p1x-p0x, e1y = p1y-p0y, e1z = p1z-p0z;
    float e2x = p2x-p0x, e2y = p2y-p0y, e2z = p2z-p0z;
    float nx = e1y*e2z - e1z*e2y;
    float ny = e1z*e2x - e1x*e2z;
    float nz = e1x*e2y - e1y*e2x;
    float S  = nx*nx + ny*ny + nz*nz + 1e-12f;
    float wt = st / (2.f * sqrtf(S));
    float dx = e1x-e2x, dy = e1y-e2y, dz = e1z-e2z;
    float g0x = wt*(dy*nz - dz*ny), g0y = wt*(dz*nx - dx*nz), g0z = wt*(dx*ny - dy*nx);
    float g1x = wt*(e2y*nz - e2z*ny), g1y = wt*(e2z*nx - e2x*nz), g1z = wt*(e2x*ny - e2y*nx);
    float g2x = wt*(ny*e1z - nz*e1y), g2y = wt*(nz*e1x - nx*e1z), g2z = wt*(nx*e1y - ny*e1x);
    float k = coeff / 6.f;
    atomicAdd(&s_gx[ia], g0x + k*q0x); atomicAdd(&s_gy[ia], g0y + k*q0y); atomicAdd(&s_gz[ia], g0z + k*q0z);
    atomicAdd(&s_gx[ib], g1x + k*q1x); atomicAdd(&s_gy[ib], g1y + k*q1y); atomicAdd(&s_gz[ib], g1z + k*q1z);
    atomicAdd(&s_gx[ic], g2x + k*q2x); atomicAdd(&s_gy[ic], g2y + k*q2y); atomicAdd(&s_gz[ic], g2z + k*q2z);
    atomicAdd(&s_csx, q0x+q1x+q2x);
    atomicAdd(&s_csy, q0y+q1y+q2y);
    atomicAdd(&s_csz, q0z+q1z+q2z);
  }
  __syncthreads();
  if (t < VP) {
    float corr = coeff / 384.f;   // coeff * (1/6) * (1/64) centroid chain
    s_fx[t] = -(s_gx[t] - corr*s_csx);
    s_fy[t] = -(s_gy[t] - corr*s_csy);
    s_fz[t] = -(s_gz[t] - corr*s_csz);
  }
  __syncthreads();
  if (t < VP) {
    int l = s_lab[t];
    bool leader = true;
    for (int s = 0; s < t; ++s) if (s_lab[s] == l) { leader = false; break; }
    if (leader) {
      float sx = 0.f, sy = 0.f, sz = 0.f;
      for (int s = t; s < VP; ++s)
        if (s_lab[s] == l) { sx += s_fx[s]; sy += s_fy[s]; sz += s_fz[s]; }
      atomicAdd(&cs2[3*l+0], sx);
      atomicAdd(&cs2[3*l+1], sy);
      atomicAdd(&cs2[3*l+2], sz);
    }
  }
}

// K5: final output = group-mean verts + dt * group-mean forces (iter 4).
__global__ __launch_bounds__(64, 1)
void k_out(const int* __restrict__ labelsF, const float* __restrict__ cs1,
           const float* __restrict__ cc1, const float* __restrict__ cs2,
           float* __restrict__ out) {
  const int c = blockIdx.x, t = threadIdx.x;
  int i = c*VP + t;
  int l = labelsF[i];
  float cc = fmaxf(cc1[l], 1.f);
  out[3*i+0] = cs1[3*l+0]/cc + 1e-5f*(cs2[3*l+0]/cc);
  out[3*i+1] = cs1[3*l+1]/cc + 1e-5f*(cs2[3*l+1]/cc);
  out[3*i+2] = cs1[3*l+2]/cc + 1e-5f*(cs2[3*l+2]/cc);
}

extern "C" void kernel_launch(void* const* d_in, const int* in_sizes, int n_in,
                              void* d_out, int out_size, void* d_ws, size_t ws_size,
                              hipStream_t stream) {
  const float* inV   = (const float*)d_in[0];
  const float* bb    = (const float*)d_in[1];
  const float* pP    = (const float*)d_in[2];
  const float* pS    = (const float*)d_in[3];
  const int*   faces = (const int*)d_in[4];
  const int*   cfl   = (const int*)d_in[6];

  char* w = (char*)d_ws;
  int*   parent  = (int*)w;   w += NV*sizeof(int);          // 32 KB
  int*   labelsF = (int*)w;   w += NV*sizeof(int);          // 32 KB
  int*   llab    = (int*)w;   w += NV*sizeof(int);          // 32 KB
  float* verts   = (float*)w; w += NV*3*sizeof(float);      // 96 KB
  float* zbase   = (float*)w;                               // contiguous zero region:
  float* sumsA   = (float*)w; w += 2*NV*3*sizeof(float);    // 192 KB (2 parities)
  float* countsA = (float*)w; w += 2*NV*sizeof(float);      // 64 KB
  float* sumsB   = (float*)w; w += 2*NV*3*sizeof(float);    // 192 KB
  ull*   masks   = (ull*)w;   w += (size_t)NC*MAXSLOT*VP*sizeof(ull);  // 1.66 MB

  hipMemsetAsync(zbase, 0, (2*NV*3 + 2*NV + 2*NV*3)*sizeof(float), stream);
  k_init<<<NV/256, 256, 0, stream>>>(parent);

  for (int it = 0; it < 5; ++it) {
    const int p = it & 1;
    float* cs1 = sumsA + p*(NV*3);
    float* cc1 = countsA + p*NV;
    float* cs2 = sumsB + p*(NV*3);
    float* ps1 = sumsA + (p^1)*(NV*3);
    float* pc  = countsA + (p^1)*NV;
    float* ps2 = sumsB + (p^1)*(NV*3);

    k_contact<<<NC, 256, 0, stream>>>(it, inV, bb, labelsF, ps1, pc, ps2,
                                      verts, llab, masks);
    k_hook<<<NC, 256, 0, stream>>>(bb, llab, masks, parent);
    k_find<<<NC, 64, 0, stream>>>(parent, llab, labelsF, verts,
                                  cs1, cc1, ps1, pc, ps2);
    k_forces<<<NC, 128, 0, stream>>>(labelsF, faces, cfl, pP, pS,
                                     cs1, cc1, cs2, parent);
  }
  // iter 4 parity = 0
  k_out<<<NC, 64, 0, stream>>>(labelsF, sumsA, countsA, sumsB, (float*)d_out);
}

// Round 14
// 568.328 us; speedup vs baseline: 1.2541x; 1.2541x over previous
//
#include <hip/hip_runtime.h>

#define NV 8192
#define NC 128
#define VP 64
#define FP 124
#define MAXSLOT 26   // bbox half-extent <= 0.5, spacing 0.8 -> <=26 neighbors
#define NSL 7        // max slots per wave = ceil(26/4)

typedef unsigned long long ull;

// ---- lock-free union-find on global parent[] ----
__device__ __forceinline__ int findro(const int* parent, int x) {
  int p = parent[x];
  while (p != x) { x = p; p = parent[x]; }
  return x;
}
__device__ __forceinline__ void ghook(int* parent, int a0, int b0) {
  int a = a0, b = b0;
  for (;;) {
    a = findro(parent, a);
    b = findro(parent, b);
    if (a == b) break;
    int hi = a > b ? a : b, lo = a > b ? b : a;
    int old = atomicMin(&parent[hi], lo);
    if (old == hi) { a = lo; b = lo; break; }
    a = old; b = lo;
  }
  int r = a < b ? a : b;
  if (r < a0) atomicMin(&parent[a0], r);   // one-shot path compression
  if (r < b0) atomicMin(&parent[b0], r);
}

// Vertex reconstruction from group-mean sums (identical expression at every
// call site -> bitwise-identical coordinates in all blocks).
__device__ __forceinline__ void recon3(const float* ps1, const float* ps2,
                                       const float* pc, int l,
                                       float& x, float& y, float& z) {
  float cc = fmaxf(pc[l], 1.f);
  x = ps1[3*l+0]/cc + 1e-5f*(ps2[3*l+0]/cc);
  y = ps1[3*l+1]/cc + 1e-5f*(ps2[3*l+1]/cc);
  z = ps1[3*l+2]/cc + 1e-5f*(ps2[3*l+2]/cc);
}

// Shared adjacency derivation: parity-balanced pair ownership.
__device__ __forceinline__ int build_adj(const float* bb, int c, int q, int v,
                                         int t, int* s_hcell, ull* s_adjw,
                                         int* s_KH) {
  if (q < 2) {
    int b = q * 64 + v;
    float anx = bb[c*6+0], any_ = bb[c*6+1], anz = bb[c*6+2];
    float axx = bb[c*6+3], axy = bb[c*6+4], axz = bb[c*6+5];
    float bnx = bb[b*6+0], bny = bb[b*6+1], bnz = bb[b*6+2];
    float bxx = bb[b*6+3], bxy = bb[b*6+4], bxz = bb[b*6+5];
    bool ov = (b != c) && (anx <= bxx) && (any_ <= bxy) && (anz <= bxz) &&
              (bnx <= axx) && (bny <= axy) && (bnz <= axz);
    bool mine = ov && (((c + b) & 1) ? (b < c) : (b > c));
    ull w = __ballot(mine);
    if (v == 0) s_adjw[q] = w;
  }
  __syncthreads();
  if (t == 0) {
    int slot = 0;
    for (int wd = 0; wd < 2; ++wd) {
      ull aw = s_adjw[wd];
      while (aw) {
        int bbit = __ffsll((long long)aw) - 1; aw &= aw - 1;
        if (slot < MAXSLOT) s_hcell[slot] = wd * 64 + bbit;
        ++slot;
      }
    }
    *s_KH = slot;
  }
  __syncthreads();
  return *s_KH;
}

__global__ void k_init(int* __restrict__ parent) {
  int i = blockIdx.x * blockDim.x + threadIdx.x;
  if (i < NV) parent[i] = i;
}

// K1: stage verts, contact masks, wave-parallel clique label propagation.
__global__ __launch_bounds__(256, 1)
void k_contact(int it, const float* __restrict__ inV, const float* __restrict__ bb,
               const int* __restrict__ labelsF, const float* __restrict__ ps1,
               const float* __restrict__ pc, const float* __restrict__ ps2,
               float* __restrict__ verts, int* __restrict__ llab,
               ull* __restrict__ masks) {
  const float T2 = (float)(0.3 * 0.3);
  const int c = blockIdx.x;
  const int t = threadIdx.x;
  const int q = t >> 6;
  const int v = t & 63;

  __shared__ float s_vx[VP], s_vy[VP], s_vz[VP], s_sq[VP];
  __shared__ int   s_ll[VP];
  __shared__ int   s_hcell[MAXSLOT];
  __shared__ int   s_KH, s_cf;
  __shared__ ull   s_adjw[2];

  const int KH = build_adj(bb, c, q, v, t, s_hcell, s_adjw, &s_KH);
  if (t == 0) s_cf = 0;

  if (t < VP) {
    int i = c*VP + t;
    float x, y, z;
    if (it == 0) { x = inV[3*i+0]; y = inV[3*i+1]; z = inV[3*i+2]; }
    else         { recon3(ps1, ps2, pc, labelsF[i], x, y, z); }
    s_vx[t] = x; s_vy[t] = y; s_vz[t] = z; s_sq[t] = x*x + y*y + z*z;
    s_ll[t] = t;
    verts[3*i+0] = x; verts[3*i+1] = y; verts[3*i+2] = z;  // for K3's scatter
  }
  __syncthreads();

  ull msk[NSL];
  {
    float xs[NSL], ys[NSL], zs[NSL];
#pragma unroll
    for (int s = 0; s < NSL; ++s) {
      msk[s] = 0;
      int slot = q + 4*s;
      if (slot < KH) {
        int jb = s_hcell[slot]*VP;
        if (it == 0) {
          int j = jb + v;
          xs[s] = inV[3*j+0]; ys[s] = inV[3*j+1]; zs[s] = inV[3*j+2];
        } else {
          int lF = labelsF[jb + v];
          recon3(ps1, ps2, pc, lF, xs[s], ys[s], zs[s]);
        }
      }
    }
#pragma unroll
    for (int s = 0; s < NSL; ++s) { int slot = q + 4*s; if (slot < KH) {
      float X = xs[s], Y = ys[s], Z = zs[s];
      float sqj = X*X + Y*Y + Z*Z;
      ull w = 0;
      for (int vv = 0; vv < VP; ++vv) {
        float d2 = s_sq[vv] + sqj - 2.f*(s_vx[vv]*X + s_vy[vv]*Y + s_vz[vv]*Z);
        if (d2 < T2) w |= (1ull << vv);
      }
      msk[s] = w;
      masks[((size_t)c*MAXSLOT + slot)*VP + v] = w;
    } }
  }

  // Pre-transpose each mask ONCE (wave-wide): tmsk on lane b = set of lanes
  // whose clique contains own-vert b.
  ull tmsk[NSL];
#pragma unroll
  for (int s = 0; s < NSL; ++s) { tmsk[s] = 0; int slot = q + 4*s; if (slot < KH) {
    ull tm = 0;
#pragma unroll
    for (int b = 0; b < 64; ++b) {
      ull w = __ballot((msk[s] >> b) & 1);
      if (v == b) tm = w;
    }
    tmsk[s] = tm;
  } }

  // Wave-parallel min-label propagation to fixpoint. Lane v holds own-vert
  // v's label in a register; cliques reduced via shfl (VALU throughput),
  // 4 waves merged through one LDS atomicMin per changed lane per round.
  {
    int ll = v;
    for (int rounds = 0; rounds < VP; ++rounds) {
      int newll = ll;
#pragma unroll
      for (int s = 0; s < NSL; ++s) {
        ull active = __ballot((msk[s] | tmsk[s]) != 0);   // wave-uniform guard
        if (active) {
          int mn = VP;
#pragma unroll
          for (int k = 0; k < 64; ++k) {
            int lk = __shfl(ll, k);
            if ((msk[s] >> k) & 1) mn = min(mn, lk);
          }
#pragma unroll
          for (int k = 0; k < 64; ++k) {
            int mk = __shfl(mn, k);
            if ((tmsk[s] >> k) & 1) newll = min(newll, mk);
          }
        }
      }
      bool chg = (newll < ll);
      if (chg) atomicMin(&s_ll[v], newll);
      if (__ballot(chg) && v == 0) s_cf = 1;
      __syncthreads();
      int done = (s_cf == 0);
      int cur = s_ll[v];
      __syncthreads();
      if (t == 0) s_cf = 0;
      ll = cur;
      if (done) break;
      __syncthreads();   // s_cf reset visible before next round's writes
    }
  }
  __syncthreads();
  if (t < VP) llab[c*VP + t] = c*VP + s_ll[t];
}

// K2: quotient-space hooks with wave dedupe of identical (L, Lb) pairs.
__global__ __launch_bounds__(256, 1)
void k_hook(const float* __restrict__ bb, const int* __restrict__ llab,
            const ull* __restrict__ masks, int* __restrict__ parent) {
  const int c = blockIdx.x;
  const int t = threadIdx.x;
  const int q = t >> 6;
  const int v = t & 63;

  __shared__ int s_hcell[MAXSLOT];
  __shared__ int s_KH;
  __shared__ ull s_adjw[2];

  const int KH = build_adj(bb, c, q, v, t, s_hcell, s_adjw, &s_KH);

#pragma unroll
  for (int s = 0; s < NSL; ++s) { int slot = q + 4*s; if (slot < KH) {
    int jb = s_hcell[slot]*VP;
    ull w = masks[((size_t)c*MAXSLOT + slot)*VP + v];
    int L = -1, Lb = -1;
    if (w) {
      L  = llab[c*VP + (__ffsll((long long)w) - 1)];  // clique-uniform
      Lb = llab[jb + v];
    }
    ull act = __ballot(w != 0);
    while (act) {
      int lead = __ffsll((long long)act) - 1;
      int Ll  = __shfl(L,  lead);
      int Lbl = __shfl(Lb, lead);
      ull grp = __ballot(L == Ll && Lb == Lbl && w != 0) & act;
      if (v == lead) ghook(parent, Ll, Lbl);
      act &= ~grp;
    }
  } }
}

// K3: find labels (starting at llab), publish, zero prev parity, scatter.
__global__ __launch_bounds__(64, 1)
void k_find(const int* __restrict__ parent, const int* __restrict__ llab,
            int* __restrict__ labelsF, const float* __restrict__ verts,
            float* __restrict__ cs1, float* __restrict__ cc1,
            float* __restrict__ zs1, float* __restrict__ zc,
            float* __restrict__ zs2) {
  const int c = blockIdx.x, t = threadIdx.x;
  __shared__ int   s_lab[VP];
  __shared__ float s_vx[VP], s_vy[VP], s_vz[VP];
  int i = c*VP + t;
  int l = findro(parent, llab[i]);
  s_lab[t] = l;
  labelsF[i] = l;
  s_vx[t] = verts[3*i+0]; s_vy[t] = verts[3*i+1]; s_vz[t] = verts[3*i+2];
  for (int idx = t; idx < VP*3; idx += VP) {
    zs1[c*VP*3 + idx] = 0.f;
    zs2[c*VP*3 + idx] = 0.f;
  }
  zc[i] = 0.f;
  __syncthreads();
  {
    bool leader = true;
    for (int s = 0; s < t; ++s) if (s_lab[s] == l) { leader = false; break; }
    if (leader) {
      float sx = 0.f, sy = 0.f, sz = 0.f, cn = 0.f;
      for (int s = t; s < VP; ++s)
        if (s_lab[s] == l) { sx += s_vx[s]; sy += s_vy[s]; sz += s_vz[s]; cn += 1.f; }
      atomicAdd(&cs1[3*l+0], sx);
      atomicAdd(&cs1[3*l+1], sy);
      atomicAdd(&cs1[3*l+2], sz);
      atomicAdd(&cc1[l], cn);
    }
  }
}

// K4: gather group-mean verts, cell forces, scatter force sums, parent reinit.
__global__ __launch_bounds__(128, 1)
void k_forces(const int* __restrict__ labelsF, const int* __restrict__ faces,
              const int* __restrict__ cfl, const float* __restrict__ pP,
              const float* __restrict__ pS,
              const float* __restrict__ cs1, const float* __restrict__ cc1,
              float* __restrict__ cs2, int* __restrict__ parent) {
  const int c = blockIdx.x, t = threadIdx.x;
  __shared__ float s_vx[VP], s_vy[VP], s_vz[VP];
  __shared__ float s_gx[VP], s_gy[VP], s_gz[VP];
  __shared__ float s_fx[VP], s_fy[VP], s_fz[VP];
  __shared__ int   s_lab[VP];
  __shared__ float s_cx, s_cy, s_cz, s_vol, s_csx, s_csy, s_csz;

  if (t < VP) {
    int i = c*VP + t;
    int l = labelsF[i];
    s_lab[t] = l;
    float cc = fmaxf(cc1[l], 1.f);
    s_vx[t] = cs1[3*l+0] / cc;
    s_vy[t] = cs1[3*l+1] / cc;
    s_vz[t] = cs1[3*l+2] / cc;
    s_gx[t] = 0.f; s_gy[t] = 0.f; s_gz[t] = 0.f;
    parent[i] = i;   // reinit for next iteration
  }
  if (t == 0) { s_vol = 0.f; s_csx = 0.f; s_csy = 0.f; s_csz = 0.f; }
  __syncthreads();
  if (t < VP) {
    float sx = s_vx[t], sy = s_vy[t], sz = s_vz[t];
#pragma unroll
    for (int o = 32; o; o >>= 1) { sx += __shfl_xor(sx, o); sy += __shfl_xor(sy, o); sz += __shfl_xor(sz, o); }
    if (t == 0) { s_cx = sx*(1.f/VP); s_cy = sy*(1.f/VP); s_cz = sz*(1.f/VP); }
  }
  __syncthreads();
  float cx = s_cx, cy = s_cy, cz = s_cz;
  bool act = (t < FP);
  int ia = 0, ib = 0, ic = 0;
  float p0x=0,p0y=0,p0z=0,p1x=0,p1y=0,p1z=0,p2x=0,p2y=0,p2z=0;
  float q0x=0,q0y=0,q0z=0;
  if (act) {
    int f = cfl[c*FP + t];
    ia = faces[3*f+0] - c*VP; ib = faces[3*f+1] - c*VP; ic = faces[3*f+2] - c*VP;
    p0x = s_vx[ia]-cx; p0y = s_vy[ia]-cy; p0z = s_vz[ia]-cz;
    p1x = s_vx[ib]-cx; p1y = s_vy[ib]-cy; p1z = s_vz[ib]-cz;
    p2x = s_vx[ic]-cx; p2y = s_vy[ic]-cy; p2z = s_vz[ic]-cz;
    q0x = p1y*p2z - p1z*p2y;
    q0y = p1z*p2x - p1x*p2z;
    q0z = p1x*p2y - p1y*p2x;
    float term = p0x*q0x + p0y*q0y + p0z*q0z;
    atomicAdd(&s_vol, term);
  }
  __syncthreads();
  float press = pP[0]*190.f + 10.f;
  float st    = pS[0]*0.018f + 0.002f;
  float tv    = expf(press / 2500.f);
  float vol   = s_vol / 6.f;
  float coeff = 2500.f * (vol - tv);
  if (act) {
    float q1x = p2y*p0z - p2z*p0y;
    float q1y = p2z*p0x - p2x*p0z;
    float q1z = p2x*p0y - p2y*p0x;
    float q2x = p0y*p1z - p0z*p1y;
    float q2y = p0z*p1x - p0x*p1z;
    float q2z = p0x*p1y - p0y*p1x;
    float e1x = p1x-p0x, e1y = p1y-p0y, e1z = p1z-p0z;
    float e2x = p2x-p0x, e2y = p2y-p0y, e2z = p2z-p0z;
    float nx = e1y*e2z - e1z*e2y;
    float ny = e1z*e2x - e1x*e2z;
    float nz = e1x*e2y - e1y*e2x;
    float S  = nx*nx + ny*ny + nz*nz + 1e-12f;
    float wt = st / (2.f * sqrtf(S));
    float dx = e1x-e2x, dy = e1y-e2y, dz = e1z-e2z;
    float g0x = wt*(dy*nz - dz*ny), g0y = wt*(dz*nx - dx*nz), g0z = wt*(dx*ny - dy*nx);
    float g1x = wt*(e2y*nz - e2z*ny), g1y = wt*(e2z*nx - e2x*nz), g1z = wt*(e2x*ny - e2y*nx);
    float g2x = wt*(ny*e1z - nz*e1y), g2y = wt*(nz*e1x - nx*e1z), g2z = wt*(nx*e1y - ny*e1x);
    float k = coeff / 6.f;
    atomicAdd(&s_gx[ia], g0x + k*q0x); atomicAdd(&s_gy[ia], g0y + k*q0y); atomicAdd(&s_gz[ia], g0z + k*q0z);
    atomicAdd(&s_gx[ib], g1x + k*q1x); atomicAdd(&s_gy[ib], g1y + k*q1y); atomicAdd(&s_gz[ib], g1z + k*q1z);
    atomicAdd(&s_gx[ic], g2x + k*q2x); atomicAdd(&s_gy[ic], g2y + k*q2y); atomicAdd(&s_gz[ic], g2z + k*q2z);
    atomicAdd(&s_csx, q0x+q1x+q2x);
    atomicAdd(&s_csy, q0y+q1y+q2y);
    atomicAdd(&s_csz, q0z+q1z+q2z);
  }
  __syncthreads();
  if (t < VP) {
    float corr = coeff / 384.f;   // coeff * (1/6) * (1/64) centroid chain
    s_fx[t] = -(s_gx[t] - corr*s_csx);
    s_fy[t] = -(s_gy[t] - corr*s_csy);
    s_fz[t] = -(s_gz[t] - corr*s_csz);
  }
  __syncthreads();
  if (t < VP) {
    int l = s_lab[t];
    bool leader = true;
    for (int s = 0; s < t; ++s) if (s_lab[s] == l) { leader = false; break; }
    if (leader) {
      float sx = 0.f, sy = 0.f, sz = 0.f;
      for (int s = t; s < VP; ++s)
        if (s_lab[s] == l) { sx += s_fx[s]; sy += s_fy[s]; sz += s_fz[s]; }
      atomicAdd(&cs2[3*l+0], sx);
      atomicAdd(&cs2[3*l+1], sy);
      atomicAdd(&cs2[3*l+2], sz);
    }
  }
}

// K5: final output = group-mean verts + dt * group-mean forces (iter 4).
__global__ __launch_bounds__(64, 1)
void k_out(const int* __restrict__ labelsF, const float* __restrict__ cs1,
           const float* __restrict__ cc1, const float* __restrict__ cs2,
           float* __restrict__ out) {
  const int c = blockIdx.x, t = threadIdx.x;
  int i = c*VP + t;
  int l = labelsF[i];
  float cc = fmaxf(cc1[l], 1.f);
  out[3*i+0] = cs1[3*l+0]/cc + 1e-5f*(cs2[3*l+0]/cc);
  out[3*i+1] = cs1[3*l+1]/cc + 1e-5f*(cs2[3*l+1]/cc);
  out[3*i+2] = cs1[3*l+2]/cc + 1e-5f*(cs2[3*l+2]/cc);
}

extern "C" void kernel_launch(void* const* d_in, const int* in_sizes, int n_in,
                              void* d_out, int out_size, void* d_ws, size_t ws_size,
                              hipStream_t stream) {
  const float* inV   = (const float*)d_in[0];
  const float* bb    = (const float*)d_in[1];
  const float* pP    = (const float*)d_in[2];
  const float* pS    = (const float*)d_in[3];
  const int*   faces = (const int*)d_in[4];
  const int*   cfl   = (const int*)d_in[6];

  char* w = (char*)d_ws;
  int*   parent  = (int*)w;   w += NV*sizeof(int);          // 32 KB
  int*   labelsF = (int*)w;   w += NV*sizeof(int);          // 32 KB
  int*   llab    = (int*)w;   w += NV*sizeof(int);          // 32 KB
  float* verts   = (float*)w; w += NV*3*sizeof(float);      // 96 KB
  float* zbase   = (float*)w;                               // contiguous zero region:
  float* sumsA   = (float*)w; w += 2*NV*3*sizeof(float);    // 192 KB (2 parities)
  float* countsA = (float*)w; w += 2*NV*sizeof(float);      // 64 KB
  float* sumsB   = (float*)w; w += 2*NV*3*sizeof(float);    // 192 KB
  ull*   masks   = (ull*)w;   w += (size_t)NC*MAXSLOT*VP*sizeof(ull);  // 1.66 MB

  hipMemsetAsync(zbase, 0, (2*NV*3 + 2*NV + 2*NV*3)*sizeof(float), stream);
  k_init<<<NV/256, 256, 0, stream>>>(parent);

  for (int it = 0; it < 5; ++it) {
    const int p = it & 1;
    float* cs1 = sumsA + p*(NV*3);
    float* cc1 = countsA + p*NV;
    float* cs2 = sumsB + p*(NV*3);
    float* ps1 = sumsA + (p^1)*(NV*3);
    float* pc  = countsA + (p^1)*NV;
    float* ps2 = sumsB + (p^1)*(NV*3);

    k_contact<<<NC, 256, 0, stream>>>(it, inV, bb, labelsF, ps1, pc, ps2,
                                      verts, llab, masks);
    k_hook<<<NC, 256, 0, stream>>>(bb, llab, masks, parent);
    k_find<<<NC, 64, 0, stream>>>(parent, llab, labelsF, verts,
                                  cs1, cc1, ps1, pc, ps2);
    k_forces<<<NC, 128, 0, stream>>>(labelsF, faces, cfl, pP, pS,
                                     cs1, cc1, cs2, parent);
  }
  // iter 4 parity = 0
  k_out<<<NC, 64, 0, stream>>>(labelsF, sumsA, countsA, sumsB, (float*)d_out);
}

// Round 15
// 411.042 us; speedup vs baseline: 1.7340x; 1.3826x over previous
//
#include <hip/hip_runtime.h>

#define NV 8192
#define NC 128
#define VP 64
#define FP 124
#define MAXSLOT 26   // bbox half-extent <= 0.5, spacing 0.8 -> <=26 neighbors
#define NSL 7        // max slots per wave = ceil(26/4)

typedef unsigned long long ull;

// ---- lock-free union-find on global parent[] ----
__device__ __forceinline__ int findro(const int* parent, int x) {
  int p = parent[x];
  while (p != x) { x = p; p = parent[x]; }
  return x;
}
__device__ __forceinline__ void ghook(int* parent, int a0, int b0) {
  int a = a0, b = b0;
  for (;;) {
    a = findro(parent, a);
    b = findro(parent, b);
    if (a == b) break;
    int hi = a > b ? a : b, lo = a > b ? b : a;
    int old = atomicMin(&parent[hi], lo);
    if (old == hi) { a = lo; b = lo; break; }
    a = old; b = lo;
  }
  int r = a < b ? a : b;
  if (r < a0) atomicMin(&parent[a0], r);   // one-shot path compression
  if (r < b0) atomicMin(&parent[b0], r);
}

// Vertex reconstruction from group-mean sums (identical expression at every
// call site -> bitwise-identical coordinates in all blocks).
__device__ __forceinline__ void recon3(const float* ps1, const float* ps2,
                                       const float* pc, int l,
                                       float& x, float& y, float& z) {
  float cc = fmaxf(pc[l], 1.f);
  x = ps1[3*l+0]/cc + 1e-5f*(ps2[3*l+0]/cc);
  y = ps1[3*l+1]/cc + 1e-5f*(ps2[3*l+1]/cc);
  z = ps1[3*l+2]/cc + 1e-5f*(ps2[3*l+2]/cc);
}

// Shared adjacency derivation: parity-balanced pair ownership.
__device__ __forceinline__ int build_adj(const float* bb, int c, int q, int v,
                                         int t, int* s_hcell, ull* s_adjw,
                                         int* s_KH) {
  if (q < 2) {
    int b = q * 64 + v;
    float anx = bb[c*6+0], any_ = bb[c*6+1], anz = bb[c*6+2];
    float axx = bb[c*6+3], axy = bb[c*6+4], axz = bb[c*6+5];
    float bnx = bb[b*6+0], bny = bb[b*6+1], bnz = bb[b*6+2];
    float bxx = bb[b*6+3], bxy = bb[b*6+4], bxz = bb[b*6+5];
    bool ov = (b != c) && (anx <= bxx) && (any_ <= bxy) && (anz <= bxz) &&
              (bnx <= axx) && (bny <= axy) && (bnz <= axz);
    bool mine = ov && (((c + b) & 1) ? (b < c) : (b > c));
    ull w = __ballot(mine);
    if (v == 0) s_adjw[q] = w;
  }
  __syncthreads();
  if (t == 0) {
    int slot = 0;
    for (int wd = 0; wd < 2; ++wd) {
      ull aw = s_adjw[wd];
      while (aw) {
        int bbit = __ffsll((long long)aw) - 1; aw &= aw - 1;
        if (slot < MAXSLOT) s_hcell[slot] = wd * 64 + bbit;
        ++slot;
      }
    }
    *s_KH = slot;
  }
  __syncthreads();
  return *s_KH;
}

__global__ void k_init(int* __restrict__ parent) {
  int i = blockIdx.x * blockDim.x + threadIdx.x;
  if (i < NV) parent[i] = i;
}

// K1: stage verts, contact masks, single-pass Warshall closure for local labels.
__global__ __launch_bounds__(256, 1)
void k_contact(int it, const float* __restrict__ inV, const float* __restrict__ bb,
               const int* __restrict__ labelsF, const float* __restrict__ ps1,
               const float* __restrict__ pc, const float* __restrict__ ps2,
               float* __restrict__ verts, int* __restrict__ llab,
               ull* __restrict__ masks) {
  const float T2 = (float)(0.3 * 0.3);
  const int c = blockIdx.x;
  const int t = threadIdx.x;
  const int q = t >> 6;
  const int v = t & 63;

  __shared__ float s_vx[VP], s_vy[VP], s_vz[VP], s_sq[VP];
  __shared__ int   s_hcell[MAXSLOT];
  __shared__ int   s_KH;
  __shared__ ull   s_adjw[2];
  __shared__ ull   s_Mw[4][VP];   // per-wave adjacency rows for merge

  const int KH = build_adj(bb, c, q, v, t, s_hcell, s_adjw, &s_KH);

  if (t < VP) {
    int i = c*VP + t;
    float x, y, z;
    if (it == 0) { x = inV[3*i+0]; y = inV[3*i+1]; z = inV[3*i+2]; }
    else         { recon3(ps1, ps2, pc, labelsF[i], x, y, z); }
    s_vx[t] = x; s_vy[t] = y; s_vz[t] = z; s_sq[t] = x*x + y*y + z*z;
    verts[3*i+0] = x; verts[3*i+1] = y; verts[3*i+2] = z;  // for K3's scatter
  }
  __syncthreads();

  ull msk[NSL];
  {
    float xs[NSL], ys[NSL], zs[NSL];
#pragma unroll
    for (int s = 0; s < NSL; ++s) {
      msk[s] = 0;
      int slot = q + 4*s;
      if (slot < KH) {
        int jb = s_hcell[slot]*VP;
        if (it == 0) {
          int j = jb + v;
          xs[s] = inV[3*j+0]; ys[s] = inV[3*j+1]; zs[s] = inV[3*j+2];
        } else {
          int lF = labelsF[jb + v];
          recon3(ps1, ps2, pc, lF, xs[s], ys[s], zs[s]);
        }
      }
    }
#pragma unroll
    for (int s = 0; s < NSL; ++s) { int slot = q + 4*s; if (slot < KH) {
      float X = xs[s], Y = ys[s], Z = zs[s];
      float sqj = X*X + Y*Y + Z*Z;
      ull w = 0;
      for (int vv = 0; vv < VP; ++vv) {
        float d2 = s_sq[vv] + sqj - 2.f*(s_vx[vv]*X + s_vy[vv]*Y + s_vz[vv]*Z);
        if (d2 < T2) w |= (1ull << vv);
      }
      msk[s] = w;
      masks[((size_t)c*MAXSLOT + slot)*VP + v] = w;
    } }
  }

  // Own-vert adjacency rows: lane v holds M_v = {own verts sharing a clique
  // with v} | {v}. Clique of neighbor-lane k in slot s = shfl(msk[s], k).
  ull M = 1ull << v;
#pragma unroll
  for (int s = 0; s < NSL; ++s) {
    ull any = __ballot(msk[s] != 0);   // wave-uniform guard
    if (any) {
#pragma unroll
      for (int k = 0; k < 64; ++k) {
        ull ck = __shfl(msk[s], k);
        if ((ck >> v) & 1) M |= ck;
      }
    }
  }
  // Merge the 4 waves' partial rows (different slots) via LDS.
  s_Mw[q][v] = M;
  __syncthreads();
  M = s_Mw[0][v] | s_Mw[1][v] | s_Mw[2][v] | s_Mw[3][v];
  // Single-pass in-wave Floyd-Warshall: full transitive closure in 64 steps.
  // At step k, shfl reads lane k's row as of step k-1 -> exact Warshall order.
#pragma unroll
  for (int k = 0; k < 64; ++k) {
    ull rk = __shfl(M, k);
    if ((M >> k) & 1) M |= rk;
  }
  if (q == 0) llab[c*VP + v] = c*VP + (__ffsll((long long)M) - 1);
}

// K2: quotient-space hooks with wave dedupe of identical (L, Lb) pairs.
__global__ __launch_bounds__(256, 1)
void k_hook(const float* __restrict__ bb, const int* __restrict__ llab,
            const ull* __restrict__ masks, int* __restrict__ parent) {
  const int c = blockIdx.x;
  const int t = threadIdx.x;
  const int q = t >> 6;
  const int v = t & 63;

  __shared__ int s_hcell[MAXSLOT];
  __shared__ int s_KH;
  __shared__ ull s_adjw[2];

  const int KH = build_adj(bb, c, q, v, t, s_hcell, s_adjw, &s_KH);

#pragma unroll
  for (int s = 0; s < NSL; ++s) { int slot = q + 4*s; if (slot < KH) {
    int jb = s_hcell[slot]*VP;
    ull w = masks[((size_t)c*MAXSLOT + slot)*VP + v];
    int L = -1, Lb = -1;
    if (w) {
      L  = llab[c*VP + (__ffsll((long long)w) - 1)];  // clique-uniform
      Lb = llab[jb + v];
    }
    ull act = __ballot(w != 0);
    while (act) {
      int lead = __ffsll((long long)act) - 1;
      int Ll  = __shfl(L,  lead);
      int Lbl = __shfl(Lb, lead);
      ull grp = __ballot(L == Ll && Lb == Lbl && w != 0) & act;
      if (v == lead) ghook(parent, Ll, Lbl);
      act &= ~grp;
    }
  } }
}

// K3: find labels (starting at llab), publish, zero prev parity, scatter.
__global__ __launch_bounds__(64, 1)
void k_find(const int* __restrict__ parent, const int* __restrict__ llab,
            int* __restrict__ labelsF, const float* __restrict__ verts,
            float* __restrict__ cs1, float* __restrict__ cc1,
            float* __restrict__ zs1, float* __restrict__ zc,
            float* __restrict__ zs2) {
  const int c = blockIdx.x, t = threadIdx.x;
  __shared__ int   s_lab[VP];
  __shared__ float s_vx[VP], s_vy[VP], s_vz[VP];
  int i = c*VP + t;
  int l = findro(parent, llab[i]);
  s_lab[t] = l;
  labelsF[i] = l;
  s_vx[t] = verts[3*i+0]; s_vy[t] = verts[3*i+1]; s_vz[t] = verts[3*i+2];
  for (int idx = t; idx < VP*3; idx += VP) {
    zs1[c*VP*3 + idx] = 0.f;
    zs2[c*VP*3 + idx] = 0.f;
  }
  zc[i] = 0.f;
  __syncthreads();
  {
    bool leader = true;
    for (int s = 0; s < t; ++s) if (s_lab[s] == l) { leader = false; break; }
    if (leader) {
      float sx = 0.f, sy = 0.f, sz = 0.f, cn = 0.f;
      for (int s = t; s < VP; ++s)
        if (s_lab[s] == l) { sx += s_vx[s]; sy += s_vy[s]; sz += s_vz[s]; cn += 1.f; }
      atomicAdd(&cs1[3*l+0], sx);
      atomicAdd(&cs1[3*l+1], sy);
      atomicAdd(&cs1[3*l+2], sz);
      atomicAdd(&cc1[l], cn);
    }
  }
}

// K4: gather group-mean verts, cell forces, scatter force sums, parent reinit.
__global__ __launch_bounds__(128, 1)
void k_forces(const int* __restrict__ labelsF, const int* __restrict__ faces,
              const int* __restrict__ cfl, const float* __restrict__ pP,
              const float* __restrict__ pS,
              const float* __restrict__ cs1, const float* __restrict__ cc1,
              float* __restrict__ cs2, int* __restrict__ parent) {
  const int c = blockIdx.x, t = threadIdx.x;
  __shared__ float s_vx[VP], s_vy[VP], s_vz[VP];
  __shared__ float s_gx[VP], s_gy[VP], s_gz[VP];
  __shared__ float s_fx[VP], s_fy[VP], s_fz[VP];
  __shared__ int   s_lab[VP];
  __shared__ float s_cx, s_cy, s_cz, s_vol, s_csx, s_csy, s_csz;

  if (t < VP) {
    int i = c*VP + t;
    int l = labelsF[i];
    s_lab[t] = l;
    float cc = fmaxf(cc1[l], 1.f);
    s_vx[t] = cs1[3*l+0] / cc;
    s_vy[t] = cs1[3*l+1] / cc;
    s_vz[t] = cs1[3*l+2] / cc;
    s_gx[t] = 0.f; s_gy[t] = 0.f; s_gz[t] = 0.f;
    parent[i] = i;   // reinit for next iteration
  }
  if (t == 0) { s_vol = 0.f; s_csx = 0.f; s_csy = 0.f; s_csz = 0.f; }
  __syncthreads();
  if (t < VP) {
    float sx = s_vx[t], sy = s_vy[t], sz = s_vz[t];
#pragma unroll
    for (int o = 32; o; o >>= 1) { sx += __shfl_xor(sx, o); sy += __shfl_xor(sy, o); sz += __shfl_xor(sz, o); }
    if (t == 0) { s_cx = sx*(1.f/VP); s_cy = sy*(1.f/VP); s_cz = sz*(1.f/VP); }
  }
  __syncthreads();
  float cx = s_cx, cy = s_cy, cz = s_cz;
  bool act = (t < FP);
  int ia = 0, ib = 0, ic = 0;
  float p0x=0,p0y=0,p0z=0,p1x=0,p1y=0,p1z=0,p2x=0,p2y=0,p2z=0;
  float q0x=0,q0y=0,q0z=0;
  if (act) {
    int f = cfl[c*FP + t];
    ia = faces[3*f+0] - c*VP; ib = faces[3*f+1] - c*VP; ic = faces[3*f+2] - c*VP;
    p0x = s_vx[ia]-cx; p0y = s_vy[ia]-cy; p0z = s_vz[ia]-cz;
    p1x = s_vx[ib]-cx; p1y = s_vy[ib]-cy; p1z = s_vz[ib]-cz;
    p2x = s_vx[ic]-cx; p2y = s_vy[ic]-cy; p2z = s_vz[ic]-cz;
    q0x = p1y*p2z - p1z*p2y;
    q0y = p1z*p2x - p1x*p2z;
    q0z = p1x*p2y - p1y*p2x;
    float term = p0x*q0x + p0y*q0y + p0z*q0z;
    atomicAdd(&s_vol, term);
  }
  __syncthreads();
  float press = pP[0]*190.f + 10.f;
  float st    = pS[0]*0.018f + 0.002f;
  float tv    = expf(press / 2500.f);
  float vol   = s_vol / 6.f;
  float coeff = 2500.f * (vol - tv);
  if (act) {
    float q1x = p2y*p0z - p2z*p0y;
    float q1y = p2z*p0x - p2x*p0z;
    float q1z = p2x*p0y - p2y*p0x;
    float q2x = p0y*p1z - p0z*p1y;
    float q2y = p0z*p1x - p0x*p1z;
    float q2z = p0x*p1y - p0y*p1x;
    float e1x = p1x-p0x, e1y = p1y-p0y, e1z = p1z-p0z;
    float e2x = p2x-p0x, e2y = p2y-p0y, e2z = p2z-p0z;
    float nx = e1y*e2z - e1z*e2y;
    float ny = e1z*e2x - e1x*e2z;
    float nz = e1x*e2y - e1y*e2x;
    float S  = nx*nx + ny*ny + nz*nz + 1e-12f;
    float wt = st / (2.f * sqrtf(S));
    float dx = e1x-e2x, dy = e1y-e2y, dz = e1z-e2z;
    float g0x = wt*(dy*nz - dz*ny), g0y = wt*(dz*nx - dx*nz), g0z = wt*(dx*ny - dy*nx);
    float g1x = wt*(e2y*nz - e2z*ny), g1y = wt*(e2z*nx - e2x*nz), g1z = wt*(e2x*ny - e2y*nx);
    float g2x = wt*(ny*e1z - nz*e1y), g2y = wt*(nz*e1x - nx*e1z), g2z = wt*(nx*e1y - ny*e1x);
    float k = coeff / 6.f;
    atomicAdd(&s_gx[ia], g0x + k*q0x); atomicAdd(&s_gy[ia], g0y + k*q0y); atomicAdd(&s_gz[ia], g0z + k*q0z);
    atomicAdd(&s_gx[ib], g1x + k*q1x); atomicAdd(&s_gy[ib], g1y + k*q1y); atomicAdd(&s_gz[ib], g1z + k*q1z);
    atomicAdd(&s_gx[ic], g2x + k*q2x); atomicAdd(&s_gy[ic], g2y + k*q2y); atomicAdd(&s_gz[ic], g2z + k*q2z);
    atomicAdd(&s_csx, q0x+q1x+q2x);
    atomicAdd(&s_csy, q0y+q1y+q2y);
    atomicAdd(&s_csz, q0z+q1z+q2z);
  }
  __syncthreads();
  if (t < VP) {
    float corr = coeff / 384.f;   // coeff * (1/6) * (1/64) centroid chain
    s_fx[t] = -(s_gx[t] - corr*s_csx);
    s_fy[t] = -(s_gy[t] - corr*s_csy);
    s_fz[t] = -(s_gz[t] - corr*s_csz);
  }
  __syncthreads();
  if (t < VP) {
    int l = s_lab[t];
    bool leader = true;
    for (int s = 0; s < t; ++s) if (s_lab[s] == l) { leader = false; break; }
    if (leader) {
      float sx = 0.f, sy = 0.f, sz = 0.f;
      for (int s = t; s < VP; ++s)
        if (s_lab[s] == l) { sx += s_fx[s]; sy += s_fy[s]; sz += s_fz[s]; }
      atomicAdd(&cs2[3*l+0], sx);
      atomicAdd(&cs2[3*l+1], sy);
      atomicAdd(&cs2[3*l+2], sz);
    }
  }
}

// K5: final output = group-mean verts + dt * group-mean forces (iter 4).
__global__ __launch_bounds__(64, 1)
void k_out(const int* __restrict__ labelsF, const float* __restrict__ cs1,
           const float* __restrict__ cc1, const float* __restrict__ cs2,
           float* __restrict__ out) {
  const int c = blockIdx.x, t = threadIdx.x;
  int i = c*VP + t;
  int l = labelsF[i];
  float cc = fmaxf(cc1[l], 1.f);
  out[3*i+0] = cs1[3*l+0]/cc + 1e-5f*(cs2[3*l+0]/cc);
  out[3*i+1] = cs1[3*l+1]/cc + 1e-5f*(cs2[3*l+1]/cc);
  out[3*i+2] = cs1[3*l+2]/cc + 1e-5f*(cs2[3*l+2]/cc);
}

extern "C" void kernel_launch(void* const* d_in, const int* in_sizes, int n_in,
                              void* d_out, int out_size, void* d_ws, size_t ws_size,
                              hipStream_t stream) {
  const float* inV   = (const float*)d_in[0];
  const float* bb    = (const float*)d_in[1];
  const float* pP    = (const float*)d_in[2];
  const float* pS    = (const float*)d_in[3];
  const int*   faces = (const int*)d_in[4];
  const int*   cfl   = (const int*)d_in[6];

  char* w = (char*)d_ws;
  int*   parent  = (int*)w;   w += NV*sizeof(int);          // 32 KB
  int*   labelsF = (int*)w;   w += NV*sizeof(int);          // 32 KB
  int*   llab    = (int*)w;   w += NV*sizeof(int);          // 32 KB
  float* verts   = (float*)w; w += NV*3*sizeof(float);      // 96 KB
  float* zbase   = (float*)w;                               // contiguous zero region:
  float* sumsA   = (float*)w; w += 2*NV*3*sizeof(float);    // 192 KB (2 parities)
  float* countsA = (float*)w; w += 2*NV*sizeof(float);      // 64 KB
  float* sumsB   = (float*)w; w += 2*NV*3*sizeof(float);    // 192 KB
  ull*   masks   = (ull*)w;   w += (size_t)NC*MAXSLOT*VP*sizeof(ull);  // 1.66 MB

  hipMemsetAsync(zbase, 0, (2*NV*3 + 2*NV + 2*NV*3)*sizeof(float), stream);
  k_init<<<NV/256, 256, 0, stream>>>(parent);

  for (int it = 0; it < 5; ++it) {
    const int p = it & 1;
    float* cs1 = sumsA + p*(NV*3);
    float* cc1 = countsA + p*NV;
    float* cs2 = sumsB + p*(NV*3);
    float* ps1 = sumsA + (p^1)*(NV*3);
    float* pc  = countsA + (p^1)*NV;
    float* ps2 = sumsB + (p^1)*(NV*3);

    k_contact<<<NC, 256, 0, stream>>>(it, inV, bb, labelsF, ps1, pc, ps2,
                                      verts, llab, masks);
    k_hook<<<NC, 256, 0, stream>>>(bb, llab, masks, parent);
    k_find<<<NC, 64, 0, stream>>>(parent, llab, labelsF, verts,
                                  cs1, cc1, ps1, pc, ps2);
    k_forces<<<NC, 128, 0, stream>>>(labelsF, faces, cfl, pP, pS,
                                     cs1, cc1, cs2, parent);
  }
  // iter 4 parity = 0
  k_out<<<NC, 64, 0, stream>>>(labelsF, sumsA, countsA, sumsB, (float*)d_out);
}